// Round 5
// baseline (2143.496 us; speedup 1.0000x reference)
//
#include <hip/hip_runtime.h>
#include <math.h>

#pragma clang fp contract(off)   // no implicit fusion; FMA only where ref has it

// Problem constants (fixed by the reference)
#define BB   8
#define NN   16384
#define FF   32
#define SS   2048
#define KK   32
#define OUTC 128

typedef float v2f __attribute__((ext_vector_type(2)));

// force a value into uniform (SGPR) representation
__device__ __forceinline__ float uni(float v) {
    return __uint_as_float(__builtin_amdgcn_readfirstlane(__float_as_uint(v)));
}

__device__ __forceinline__ v2f splat2(float s) { v2f r; r.x = s; r.y = s; return r; }

// prefix popcount of 64-bit ballot below this lane (2 VALU ops)
__device__ __forceinline__ int mbcnt64(unsigned long long m) {
    return __builtin_amdgcn_mbcnt_hi((unsigned)(m >> 32),
           __builtin_amdgcn_mbcnt_lo((unsigned)m, 0));
}

// ---------------------------------------------------------------------------
// Reference-bit-exact fp32 helpers (validated R0-R7):
// x_sq / s_sq: numpy pairwise_sum scalar 8-accumulator block (n=32, no FMA)
__device__ __forceinline__ float np_sumsq32(const float* a) {
    float r[8];
#pragma unroll
    for (int j = 0; j < 8; j++) r[j] = a[j] * a[j];
#pragma unroll
    for (int t = 1; t < 4; t++) {
#pragma unroll
        for (int j = 0; j < 8; j++) {
            float e = a[8 * t + j] * a[8 * t + j];
            r[j] = r[j] + e;
        }
    }
    return ((r[0] + r[1]) + (r[2] + r[3])) + ((r[4] + r[5]) + (r[6] + r[7]));
}

// ---------------------------------------------------------------------------
// K1a: x_sq[b,n] = ref-order sum_f x^2
__global__ __launch_bounds__(256) void xsq_kernel(const float* __restrict__ x,
                                                  float* __restrict__ xsq) {
    int gid = blockIdx.x * 256 + threadIdx.x;      // < B*N
    const float4* r = (const float4*)(x + (size_t)gid * FF);
    float a[32];
#pragma unroll
    for (int j = 0; j < 8; j++) {
        float4 v = r[j];
        a[4 * j] = v.x; a[4 * j + 1] = v.y; a[4 * j + 2] = v.z; a[4 * j + 3] = v.w;
    }
    xsq[gid] = np_sumsq32(a);
}

// ---------------------------------------------------------------------------
// K1b: gather sampled features (row-major [B,S,F]) + ref-order s_sq
__global__ __launch_bounds__(256) void gather_kernel(const float* __restrict__ x,
                                                     const int* __restrict__ sidx,
                                                     float* __restrict__ sampled,
                                                     float* __restrict__ ssq) {
    int gid = blockIdx.x * 256 + threadIdx.x;      // < B*S
    int b = gid >> 11;
    int idx = sidx[gid];
    const float4* r = (const float4*)(x + ((size_t)b * NN + idx) * FF);
    float4* wo = (float4*)(sampled + (size_t)gid * FF);
    float a[32];
#pragma unroll
    for (int j = 0; j < 8; j++) {
        float4 v = r[j];
        a[4 * j] = v.x; a[4 * j + 1] = v.y; a[4 * j + 2] = v.z; a[4 * j + 3] = v.w;
        wo[j] = v;
    }
    ssq[gid] = np_sumsq32(a);
}

// ---------------------------------------------------------------------------
// K1c: sampled [B,S,F] -> output sampled_batch [B,F,S] (transpose via LDS)
__global__ __launch_bounds__(256) void transpose_kernel(const float* __restrict__ sampled,
                                                        float* __restrict__ out_samp) {
    __shared__ float tile[32][65];
    int b = blockIdx.x >> 5, sg = blockIdx.x & 31;
    int s0 = sg * 64;
    int tid = threadIdx.x;
    int f = tid & 31, si = tid >> 5;               // si in 0..7
#pragma unroll
    for (int r = 0; r < 8; r++) {
        int s = r * 8 + si;
        tile[f][s] = sampled[((size_t)b * SS + s0 + s) * FF + f];
    }
    __syncthreads();
#pragma unroll
    for (int r = 0; r < 8; r++) {
        int flat = r * 256 + tid;
        int fo = flat >> 6, sw = flat & 63;
        out_samp[((size_t)b * FF + fo) * SS + s0 + sw] = tile[fo][sw];
    }
}

// ---------------------------------------------------------------------------
// K2: per-point MLP, h2[b,n,:] = W2 @ relu(W1 @ x + b1) + b2  (fp32, VALU)
__global__ __launch_bounds__(256) void mlp_kernel(const float* __restrict__ x,
                                                  const float* __restrict__ W1,
                                                  const float* __restrict__ b1,
                                                  const float* __restrict__ W2,
                                                  const float* __restrict__ b2,
                                                  float* __restrict__ h2) {
    __shared__ float xs[64][36];          // padded
    __shared__ float hs[8512];            // h1t [128][65] then reused as h2s [64][133]
    int tid = threadIdx.x, lane = tid & 63;
    int wu = __builtin_amdgcn_readfirstlane(tid >> 6);
    size_t p0 = (size_t)blockIdx.x * 64;

    for (int i = tid; i < 64 * 8; i += 256) {
        int row = i >> 3, seg = i & 7;
        *(float4*)&xs[row][seg * 4] = *(const float4*)(x + (p0 + row) * FF + seg * 4);
    }
    __syncthreads();

    float xr[32];
    {
        const float4* r = (const float4*)&xs[lane][0];
#pragma unroll
        for (int j = 0; j < 8; j++) {
            float4 v = r[j];
            xr[4 * j] = v.x; xr[4 * j + 1] = v.y; xr[4 * j + 2] = v.z; xr[4 * j + 3] = v.w;
        }
    }
#pragma unroll 4
    for (int i = 0; i < 32; i++) {
        int o = wu * 32 + i;
        const float4* wr = (const float4*)(W1 + o * FF);
        float a = b1[o];
#pragma unroll
        for (int j = 0; j < 8; j++) {
            float4 v = wr[j];
            a = fmaf(v.x, xr[4 * j], a);     a = fmaf(v.y, xr[4 * j + 1], a);
            a = fmaf(v.z, xr[4 * j + 2], a); a = fmaf(v.w, xr[4 * j + 3], a);
        }
        hs[o * 65 + lane] = fmaxf(a, 0.f);
    }
    __syncthreads();
    float acc[32];
#pragma unroll
    for (int i = 0; i < 32; i++) acc[i] = b2[wu * 32 + i];
    for (int k4 = 0; k4 < 32; k4++) {
        float h0 = hs[(4 * k4 + 0) * 65 + lane];
        float h1v = hs[(4 * k4 + 1) * 65 + lane];
        float h2v = hs[(4 * k4 + 2) * 65 + lane];
        float h3v = hs[(4 * k4 + 3) * 65 + lane];
#pragma unroll
        for (int i = 0; i < 32; i++) {
            const float4 v = *(const float4*)(W2 + (wu * 32 + i) * OUTC + 4 * k4);
            acc[i] = fmaf(v.x, h0, acc[i]);  acc[i] = fmaf(v.y, h1v, acc[i]);
            acc[i] = fmaf(v.z, h2v, acc[i]); acc[i] = fmaf(v.w, h3v, acc[i]);
        }
    }
    __syncthreads();
#pragma unroll 4
    for (int i = 0; i < 32; i++) hs[lane * 133 + wu * 32 + i] = acc[i];
    __syncthreads();
    for (int j = 0; j < 32; j++) {
        int flat = j * 256 + tid;
        int p = flat >> 7, o = flat & 127;
        h2[(p0 + p) * OUTC + o] = hs[p * 133 + o];
    }
}

// ---------------------------------------------------------------------------
// K3 v8: register-direct distance loop — NO LDS x-tile, NO barriers.
// R4 post-mortem: wall is 7x the VALU-issue floor; suspects are (a) 8-way
// LDS bank conflict on xs row reads (stride 36 dwords -> bank 4*lane mod 32;
// any 16B-aligned stride gives >=8-way for row-per-lane) and (b) 2 barriers
// per tile coupling 4 waves x 256 iters. Fix: each lane loads its own point
// row straight from global (L2-resident: x panel = 2MB/batch, XCD-by-batch
// swizzle means all blocks on an XCD stream the SAME panel; L2/XCD = 4MB).
// Register A/B double-buffer, one tile of prefetch distance. bufd/bufi are
// per-wave so the kernel needs no __syncthreads at all.
__device__ __forceinline__ bool lessp(float da, int ia, float db, int ib) {
    return da < db || (da == db && ia < ib);
}
__device__ __forceinline__ void cswap(float& d, int& i, int j, bool dirAsc, int lane) {
    float od = __shfl_xor(d, j);
    int   oi = __shfl_xor(i, j);
    bool lower = (lane & j) == 0;
    bool oLess = lessp(od, oi, d, i);
    if (oLess == (lower == dirAsc)) { d = od; i = oi; }
}
__device__ __forceinline__ void sort64(float& d, int& i, bool asc, int lane) {
#pragma unroll
    for (int k = 2; k <= 64; k <<= 1) {
        bool ba = (((lane & k) == 0) == asc);
#pragma unroll
        for (int j = k >> 1; j > 0; j >>= 1) cswap(d, i, j, ba, lane);
    }
}
// sort m valid slots, keep lowest-64 lex-sorted in [0,64); return 32nd-smallest
__device__ __forceinline__ float wave_compact2(float* bd, int* bi, int m, int lane) {
    float d0 = (lane < m) ? bd[lane] : INFINITY;
    int   i0 = (lane < m) ? bi[lane] : 0x7fffffff;
    float d1 = (lane + 64 < m) ? bd[lane + 64] : INFINITY;
    int   i1 = (lane + 64 < m) ? bi[lane + 64] : 0x7fffffff;
    sort64(d0, i0, true, lane);
    sort64(d1, i1, false, lane);
    bool t = lessp(d1, i1, d0, i0);
    float ld = t ? d1 : d0;
    int   li = t ? i1 : i0;
#pragma unroll
    for (int j = 32; j > 0; j >>= 1) cswap(ld, li, j, true, lane);
    bd[lane] = ld; bi[lane] = li;
    return uni(__shfl(ld, 31));            // uniform across wave
}

__device__ __forceinline__ void insert_cand(float dv, int n, int lane,
                                            float* bd, int* bi, int& cnt, float& tau) {
    unsigned long long m = __ballot(dv < tau);
    if (m) {
        int pos = cnt + mbcnt64(m);
        if (dv < tau) { bd[pos] = dv; bi[pos] = n; }
        cnt += __builtin_popcountll(m);
        if (cnt > 64) { tau = wave_compact2(bd, bi, cnt, lane); cnt = 32; }
    }
}

__device__ __forceinline__ void tile_pass(const float4* buf, int t, float xq, int lane,
                                          const v2f* qp, v2f ssq01,
                                          float* bq0d, int* bq0i, int& cnt0, float& tau0,
                                          float* bq1d, int* bq1i, int& cnt1, float& tau1) {
    // packed dot chains: .x = query0, .y = query1; each half is the
    // ref-exact sequential FMA order (v_pk_fma_f32 per-half = fmaf)
    v2f c01; c01.x = 0.f; c01.y = 0.f;
#pragma unroll
    for (int j = 0; j < 8; j++) {
        float4 v = buf[j];
        c01 = __builtin_elementwise_fma(qp[4 * j + 0], splat2(v.x), c01);
        c01 = __builtin_elementwise_fma(qp[4 * j + 1], splat2(v.y), c01);
        c01 = __builtin_elementwise_fma(qp[4 * j + 2], splat2(v.z), c01);
        c01 = __builtin_elementwise_fma(qp[4 * j + 3], splat2(v.w), c01);
    }
    // ref combine order per half: (ssq + xq) - (c + c)
    v2f d01 = (ssq01 + splat2(xq)) - (c01 + c01);
    int n = t * 64 + lane;
    insert_cand(d01.x, n, lane, bq0d, bq0i, cnt0, tau0);
    insert_cand(d01.y, n, lane, bq1d, bq1i, cnt1, tau1);
}

__global__ __launch_bounds__(256, 4) void topk_kernel(const float* __restrict__ x,
                                                      const float* __restrict__ x_sq,
                                                      const float* __restrict__ sampled,
                                                      const float* __restrict__ s_sq,
                                                      int* __restrict__ nbr) {
    int b = blockIdx.x & 7;                 // XCD-by-batch swizzle
    int qg = blockIdx.x >> 3;               // 0..255
    int tid = threadIdx.x, lane = tid & 63;
    int w = __builtin_amdgcn_readfirstlane(tid >> 6);
    __shared__ float bufd[8][128];
    __shared__ int   bufi[8][128];
    int s0 = qg * 8;                        // 8 queries per block, 2 per wave
    const float* xb = x + (size_t)b * (NN * FF);
    const float* xqb = x_sq + (size_t)b * NN;

    // 2 query feature vectors, packed {q0,q1} pairs -> wave-uniform (SGPR pairs)
    v2f qp[32];
    {
        const float* sp0 = sampled + ((size_t)b * SS + s0 + w * 2 + 0) * FF;
        const float* sp1 = sampled + ((size_t)b * SS + s0 + w * 2 + 1) * FF;
#pragma unroll
        for (int k = 0; k < 32; k++) {
            qp[k].x = uni(sp0[k]);
            qp[k].y = uni(sp1[k]);
        }
    }
    v2f ssq01;
    ssq01.x = uni(s_sq[b * SS + s0 + w * 2 + 0]);
    ssq01.y = uni(s_sq[b * SS + s0 + w * 2 + 1]);

    float* bq0d = &bufd[w * 2 + 0][0];  int* bq0i = &bufi[w * 2 + 0][0];
    float* bq1d = &bufd[w * 2 + 1][0];  int* bq1i = &bufi[w * 2 + 1][0];
    int   cnt0 = 0, cnt1 = 0;              // wave-uniform (ballot popcounts)
    float tau0 = INFINITY, tau1 = INFINITY;

    // per-lane row pointer: lane l owns point t*64+l of each tile
    const float4* lp = (const float4*)xb + (size_t)lane * 8;
    float4 bufA[8], bufB[8];
    float xqA, xqB;
#pragma unroll
    for (int j = 0; j < 8; j++) bufA[j] = lp[j];        // tile 0
    xqA = xqb[lane];

    for (int t = 0; t < NN / 64; t += 2) {
        // prefetch tile t+1 -> B (in flight across tile t's compute)
#pragma unroll
        for (int j = 0; j < 8; j++) bufB[j] = lp[(size_t)(t + 1) * 512 + j];
        xqB = xqb[(t + 1) * 64 + lane];

        tile_pass(bufA, t, xqA, lane, qp, ssq01,
                  bq0d, bq0i, cnt0, tau0, bq1d, bq1i, cnt1, tau1);

        // prefetch tile t+2 -> A
        if (t + 2 < NN / 64) {
#pragma unroll
            for (int j = 0; j < 8; j++) bufA[j] = lp[(size_t)(t + 2) * 512 + j];
            xqA = xqb[(t + 2) * 64 + lane];
        }

        tile_pass(bufB, t + 1, xqB, lane, qp, ssq01,
                  bq0d, bq0i, cnt0, tau0, bq1d, bq1i, cnt1, tau1);
    }
    // final: compact (lex-sorts survivors) and emit first 32 per query
    wave_compact2(bq0d, bq0i, cnt0, lane);
    wave_compact2(bq1d, bq1i, cnt1, lane);
    int s = s0 + w * 2;
    if (lane < 32) {
        nbr[((size_t)b * SS + s) * KK + lane] = bq0i[lane];
        nbr[((size_t)b * SS + s + 1) * KK + lane] = bq1i[lane];
    }
}

// ---------------------------------------------------------------------------
// K4: features_batch[b,o,s] = max_k h2[b, nbr[b,s,k], o]; block=128, 16 s/block
__global__ __launch_bounds__(128) void maxgather_kernel(const float* __restrict__ h2,
                                                        const int* __restrict__ nbr,
                                                        float* __restrict__ out_feat) {
    __shared__ float fs[128][17];
    int b = blockIdx.x & 7;
    int sg = blockIdx.x >> 3;               // 0..127
    int s0 = sg * 16;
    int tid = threadIdx.x;                  // o = tid (0..127)
    for (int si = 0; si < 16; si++) {
        int s = s0 + si;
        const int* row = nbr + ((size_t)b * SS + s) * KK;
        float m = -INFINITY;
#pragma unroll 4
        for (int k = 0; k < KK; k++) {
            int idx = row[k];
            float v = h2[((size_t)b * NN + idx) * OUTC + tid];
            m = fmaxf(m, v);
        }
        fs[tid][si] = m;
    }
    __syncthreads();
#pragma unroll
    for (int j = 0; j < 16; j++) {
        int flat = j * 128 + tid;
        int fo = flat >> 4, sw = flat & 15;
        out_feat[((size_t)b * OUTC + fo) * SS + s0 + sw] = fs[fo][sw];
    }
}

// ---------------------------------------------------------------------------
extern "C" void kernel_launch(void* const* d_in, const int* in_sizes, int n_in,
                              void* d_out, int out_size, void* d_ws, size_t ws_size,
                              hipStream_t stream) {
    const float* x    = (const float*)d_in[0];
    const int*   sidx = (const int*)d_in[1];
    const float* W1   = (const float*)d_in[2];
    const float* b1   = (const float*)d_in[3];
    const float* W2   = (const float*)d_in[4];
    const float* b2   = (const float*)d_in[5];

    float* out_feat = (float*)d_out;                       // [B,128,S]
    float* out_samp = out_feat + (size_t)BB * OUTC * SS;   // [B,32,S]

    float* h2      = (float*)d_ws;                         // B*N*128 fp32 = 64 MB
    float* sampled = h2 + (size_t)BB * NN * OUTC;          // B*S*F
    float* xsq     = sampled + (size_t)BB * SS * FF;       // B*N
    float* ssq     = xsq + (size_t)BB * NN;                // B*S
    int*   nbr     = (int*)(ssq + (size_t)BB * SS);        // B*S*K

    xsq_kernel<<<dim3(BB * NN / 256), dim3(256), 0, stream>>>(x, xsq);
    gather_kernel<<<dim3(BB * SS / 256), dim3(256), 0, stream>>>(x, sidx, sampled, ssq);
    mlp_kernel<<<dim3(BB * NN / 64), dim3(256), 0, stream>>>(x, W1, b1, W2, b2, h2);
    transpose_kernel<<<dim3(BB * SS / 64), dim3(256), 0, stream>>>(sampled, out_samp);
    topk_kernel<<<dim3(BB * SS / 8), dim3(256), 0, stream>>>(x, xsq, sampled, ssq, nbr);
    maxgather_kernel<<<dim3(BB * SS / 16), dim3(128), 0, stream>>>(h2, nbr, out_feat);
}

// Round 6
// 1146.317 us; speedup vs baseline: 1.8699x; 1.8699x over previous
//
#include <hip/hip_runtime.h>
#include <math.h>

#pragma clang fp contract(off)   // no implicit fusion; FMA only where ref has it

// Problem constants (fixed by the reference)
#define BB   8
#define NN   16384
#define FF   32
#define SS   2048
#define KK   32
#define OUTC 128

typedef float v2f __attribute__((ext_vector_type(2)));

// force a value into uniform (SGPR) representation
__device__ __forceinline__ float uni(float v) {
    return __uint_as_float(__builtin_amdgcn_readfirstlane(__float_as_uint(v)));
}

__device__ __forceinline__ v2f splat2(float s) { v2f r; r.x = s; r.y = s; return r; }

// prefix popcount of 64-bit ballot below this lane (2 VALU ops)
__device__ __forceinline__ int mbcnt64(unsigned long long m) {
    return __builtin_amdgcn_mbcnt_hi((unsigned)(m >> 32),
           __builtin_amdgcn_mbcnt_lo((unsigned)m, 0));
}

// ---------------------------------------------------------------------------
// Reference-bit-exact fp32 helpers (validated R0-R7):
// x_sq / s_sq: numpy pairwise_sum scalar 8-accumulator block (n=32, no FMA)
__device__ __forceinline__ float np_sumsq32(const float* a) {
    float r[8];
#pragma unroll
    for (int j = 0; j < 8; j++) r[j] = a[j] * a[j];
#pragma unroll
    for (int t = 1; t < 4; t++) {
#pragma unroll
        for (int j = 0; j < 8; j++) {
            float e = a[8 * t + j] * a[8 * t + j];
            r[j] = r[j] + e;
        }
    }
    return ((r[0] + r[1]) + (r[2] + r[3])) + ((r[4] + r[5]) + (r[6] + r[7]));
}

// ---------------------------------------------------------------------------
// K1a: x_sq[b,n] = ref-order sum_f x^2
__global__ __launch_bounds__(256) void xsq_kernel(const float* __restrict__ x,
                                                  float* __restrict__ xsq) {
    int gid = blockIdx.x * 256 + threadIdx.x;      // < B*N
    const float4* r = (const float4*)(x + (size_t)gid * FF);
    float a[32];
#pragma unroll
    for (int j = 0; j < 8; j++) {
        float4 v = r[j];
        a[4 * j] = v.x; a[4 * j + 1] = v.y; a[4 * j + 2] = v.z; a[4 * j + 3] = v.w;
    }
    xsq[gid] = np_sumsq32(a);
}

// ---------------------------------------------------------------------------
// K1b: gather sampled features (row-major [B,S,F]) + ref-order s_sq
__global__ __launch_bounds__(256) void gather_kernel(const float* __restrict__ x,
                                                     const int* __restrict__ sidx,
                                                     float* __restrict__ sampled,
                                                     float* __restrict__ ssq) {
    int gid = blockIdx.x * 256 + threadIdx.x;      // < B*S
    int b = gid >> 11;
    int idx = sidx[gid];
    const float4* r = (const float4*)(x + ((size_t)b * NN + idx) * FF);
    float4* wo = (float4*)(sampled + (size_t)gid * FF);
    float a[32];
#pragma unroll
    for (int j = 0; j < 8; j++) {
        float4 v = r[j];
        a[4 * j] = v.x; a[4 * j + 1] = v.y; a[4 * j + 2] = v.z; a[4 * j + 3] = v.w;
        wo[j] = v;
    }
    ssq[gid] = np_sumsq32(a);
}

// ---------------------------------------------------------------------------
// K1c: sampled [B,S,F] -> output sampled_batch [B,F,S] (transpose via LDS)
__global__ __launch_bounds__(256) void transpose_kernel(const float* __restrict__ sampled,
                                                        float* __restrict__ out_samp) {
    __shared__ float tile[32][65];
    int b = blockIdx.x >> 5, sg = blockIdx.x & 31;
    int s0 = sg * 64;
    int tid = threadIdx.x;
    int f = tid & 31, si = tid >> 5;               // si in 0..7
#pragma unroll
    for (int r = 0; r < 8; r++) {
        int s = r * 8 + si;
        tile[f][s] = sampled[((size_t)b * SS + s0 + s) * FF + f];
    }
    __syncthreads();
#pragma unroll
    for (int r = 0; r < 8; r++) {
        int flat = r * 256 + tid;
        int fo = flat >> 6, sw = flat & 63;
        out_samp[((size_t)b * FF + fo) * SS + s0 + sw] = tile[fo][sw];
    }
}

// ---------------------------------------------------------------------------
// K2: per-point MLP, h2[b,n,:] = W2 @ relu(W1 @ x + b1) + b2  (fp32, VALU)
__global__ __launch_bounds__(256) void mlp_kernel(const float* __restrict__ x,
                                                  const float* __restrict__ W1,
                                                  const float* __restrict__ b1,
                                                  const float* __restrict__ W2,
                                                  const float* __restrict__ b2,
                                                  float* __restrict__ h2) {
    __shared__ float xs[64][36];          // padded
    __shared__ float hs[8512];            // h1t [128][65] then reused as h2s [64][133]
    int tid = threadIdx.x, lane = tid & 63;
    int wu = __builtin_amdgcn_readfirstlane(tid >> 6);
    size_t p0 = (size_t)blockIdx.x * 64;

    for (int i = tid; i < 64 * 8; i += 256) {
        int row = i >> 3, seg = i & 7;
        *(float4*)&xs[row][seg * 4] = *(const float4*)(x + (p0 + row) * FF + seg * 4);
    }
    __syncthreads();

    float xr[32];
    {
        const float4* r = (const float4*)&xs[lane][0];
#pragma unroll
        for (int j = 0; j < 8; j++) {
            float4 v = r[j];
            xr[4 * j] = v.x; xr[4 * j + 1] = v.y; xr[4 * j + 2] = v.z; xr[4 * j + 3] = v.w;
        }
    }
#pragma unroll 4
    for (int i = 0; i < 32; i++) {
        int o = wu * 32 + i;
        const float4* wr = (const float4*)(W1 + o * FF);
        float a = b1[o];
#pragma unroll
        for (int j = 0; j < 8; j++) {
            float4 v = wr[j];
            a = fmaf(v.x, xr[4 * j], a);     a = fmaf(v.y, xr[4 * j + 1], a);
            a = fmaf(v.z, xr[4 * j + 2], a); a = fmaf(v.w, xr[4 * j + 3], a);
        }
        hs[o * 65 + lane] = fmaxf(a, 0.f);
    }
    __syncthreads();
    float acc[32];
#pragma unroll
    for (int i = 0; i < 32; i++) acc[i] = b2[wu * 32 + i];
    for (int k4 = 0; k4 < 32; k4++) {
        float h0 = hs[(4 * k4 + 0) * 65 + lane];
        float h1v = hs[(4 * k4 + 1) * 65 + lane];
        float h2v = hs[(4 * k4 + 2) * 65 + lane];
        float h3v = hs[(4 * k4 + 3) * 65 + lane];
#pragma unroll
        for (int i = 0; i < 32; i++) {
            const float4 v = *(const float4*)(W2 + (wu * 32 + i) * OUTC + 4 * k4);
            acc[i] = fmaf(v.x, h0, acc[i]);  acc[i] = fmaf(v.y, h1v, acc[i]);
            acc[i] = fmaf(v.z, h2v, acc[i]); acc[i] = fmaf(v.w, h3v, acc[i]);
        }
    }
    __syncthreads();
#pragma unroll 4
    for (int i = 0; i < 32; i++) hs[lane * 133 + wu * 32 + i] = acc[i];
    __syncthreads();
    for (int j = 0; j < 32; j++) {
        int flat = j * 256 + tid;
        int p = flat >> 7, o = flat & 127;
        h2[(p0 + p) * OUTC + o] = hs[p * 133 + o];
    }
}

// ---------------------------------------------------------------------------
// K3 v9: back to R4's staged-LDS structure (R5's per-lane global rows were
// uncoalesced: 64 cache lines per load instr vs 8 staged -> 8x L2 request
// traffic, VALUBusy 18%, 2.4x regression. R4's LDS reads were in fact
// conflict-free on re-analysis: per 128B/clk phase, 8 lanes with distinct
// l&7 hit distinct bank quads; SQ_LDS_BANK_CONFLICT=0 was truthful).
// Change vs R4: 4 QUERIES PER WAVE (16/block, 1024 blocks). The plateau
// (780-840us across R0/R3/R4 at ~49% VALUBusy) is per-tile fixed cost
// (stage, 2 barriers, LDS/prefetch latency), not FMA issue (~60-130us).
// Doubling queries/wave halves total tile-phases and their fixed cost;
// same 8 ds_read_b128 now feed 64 v_pk_fma. q0,q1 -> SGPR pairs (uni),
// q2,q3 -> VGPR pairs (SGPR file is at budget; v_pk_fma takes VGPR srcs).
__device__ __forceinline__ bool lessp(float da, int ia, float db, int ib) {
    return da < db || (da == db && ia < ib);
}
__device__ __forceinline__ void cswap(float& d, int& i, int j, bool dirAsc, int lane) {
    float od = __shfl_xor(d, j);
    int   oi = __shfl_xor(i, j);
    bool lower = (lane & j) == 0;
    bool oLess = lessp(od, oi, d, i);
    if (oLess == (lower == dirAsc)) { d = od; i = oi; }
}
__device__ __forceinline__ void sort64(float& d, int& i, bool asc, int lane) {
#pragma unroll
    for (int k = 2; k <= 64; k <<= 1) {
        bool ba = (((lane & k) == 0) == asc);
#pragma unroll
        for (int j = k >> 1; j > 0; j >>= 1) cswap(d, i, j, ba, lane);
    }
}
// sort m valid slots, keep lowest-64 lex-sorted in [0,64); return 32nd-smallest
__device__ __forceinline__ float wave_compact2(float* bd, int* bi, int m, int lane) {
    float d0 = (lane < m) ? bd[lane] : INFINITY;
    int   i0 = (lane < m) ? bi[lane] : 0x7fffffff;
    float d1 = (lane + 64 < m) ? bd[lane + 64] : INFINITY;
    int   i1 = (lane + 64 < m) ? bi[lane + 64] : 0x7fffffff;
    sort64(d0, i0, true, lane);
    sort64(d1, i1, false, lane);
    bool t = lessp(d1, i1, d0, i0);
    float ld = t ? d1 : d0;
    int   li = t ? i1 : i0;
#pragma unroll
    for (int j = 32; j > 0; j >>= 1) cswap(ld, li, j, true, lane);
    bd[lane] = ld; bi[lane] = li;
    return uni(__shfl(ld, 31));            // uniform across wave
}

__device__ __forceinline__ void insert_cand(float dv, int n, int lane,
                                            float* bd, int* bi, int& cnt, float& tau) {
    unsigned long long m = __ballot(dv < tau);
    if (m) {
        int pos = cnt + mbcnt64(m);
        if (dv < tau) { bd[pos] = dv; bi[pos] = n; }
        cnt += __builtin_popcountll(m);
        if (cnt > 64) { tau = wave_compact2(bd, bi, cnt, lane); cnt = 32; }
    }
}

__global__ __launch_bounds__(256, 4) void topk_kernel(const float* __restrict__ x,
                                                      const float* __restrict__ x_sq,
                                                      const float* __restrict__ sampled,
                                                      const float* __restrict__ s_sq,
                                                      int* __restrict__ nbr) {
    int b = blockIdx.x & 7;                 // XCD-by-batch swizzle
    int qg = blockIdx.x >> 3;               // 0..127
    int tid = threadIdx.x, lane = tid & 63;
    int w = __builtin_amdgcn_readfirstlane(tid >> 6);
    __shared__ float xs[64][36];            // single buffer, padded rows (9216 B)
    __shared__ float bufd[16][128];
    __shared__ int   bufi[16][128];
    int s0 = qg * 16;                       // 16 queries per block, 4 per wave
    const float* xb = x + (size_t)b * (NN * FF);
    const float* xqb = x_sq + (size_t)b * NN;

    // 4 query vectors: q0,q1 packed in SGPR pairs (uni); q2,q3 in VGPR pairs
    v2f qpA[32], qpB[32];
    {
        const float* sp0 = sampled + ((size_t)b * SS + s0 + w * 4 + 0) * FF;
        const float* sp1 = sampled + ((size_t)b * SS + s0 + w * 4 + 1) * FF;
        const float* sp2 = sampled + ((size_t)b * SS + s0 + w * 4 + 2) * FF;
        const float* sp3 = sampled + ((size_t)b * SS + s0 + w * 4 + 3) * FF;
#pragma unroll
        for (int k = 0; k < 32; k++) {
            qpA[k].x = uni(sp0[k]);
            qpA[k].y = uni(sp1[k]);
            qpB[k].x = sp2[k];
            qpB[k].y = sp3[k];
        }
    }
    v2f ssqA, ssqB;
    ssqA.x = uni(s_sq[b * SS + s0 + w * 4 + 0]);
    ssqA.y = uni(s_sq[b * SS + s0 + w * 4 + 1]);
    ssqB.x = s_sq[b * SS + s0 + w * 4 + 2];
    ssqB.y = s_sq[b * SS + s0 + w * 4 + 3];

    float* bq0d = &bufd[w * 4 + 0][0];  int* bq0i = &bufi[w * 4 + 0][0];
    float* bq1d = &bufd[w * 4 + 1][0];  int* bq1i = &bufi[w * 4 + 1][0];
    float* bq2d = &bufd[w * 4 + 2][0];  int* bq2i = &bufi[w * 4 + 2][0];
    float* bq3d = &bufd[w * 4 + 3][0];  int* bq3i = &bufi[w * 4 + 3][0];
    int   cnt0 = 0, cnt1 = 0, cnt2 = 0, cnt3 = 0;   // wave-uniform
    float tau0 = INFINITY, tau1 = INFINITY, tau2 = INFINITY, tau3 = INFINITY;

    // staging geometry: thread stages rows r0 and r0+32, 16B chunk c0
    int r0 = tid >> 3, c0 = (tid & 7) * 4;
    const float4* g0 = (const float4*)(xb + (size_t)r0 * FF + c0);
    const float4* g1 = (const float4*)(xb + (size_t)(r0 + 32) * FF + c0);
    // preamble: tile 0 -> regs; x_sq tile 0 -> reg
    float4 p0 = g0[0], p1 = g1[0];
    float xq = xqb[lane];

    for (int t = 0; t < NN / 64; t++) {
        // write tile t (regs -> LDS), then issue prefetch of tile t+1
        *(float4*)&xs[r0][c0] = p0;
        *(float4*)&xs[r0 + 32][c0] = p1;
        if (t + 1 < NN / 64) {
            p0 = g0[(size_t)(t + 1) * 512];   // 512 float4 = 64 rows
            p1 = g1[(size_t)(t + 1) * 512];
        }
        __syncthreads();                      // tile t writes visible
        float xq_c = xq;
        if (t + 1 < NN / 64) xq = xqb[(t + 1) * 64 + lane];

        // 2 packed dot-chain pairs on the same LDS row; each half is the
        // ref-exact sequential FMA order (v_pk_fma_f32 per-half = fmaf)
        v2f cA; cA.x = 0.f; cA.y = 0.f;
        v2f cB; cB.x = 0.f; cB.y = 0.f;
        {
            const float4* rr = (const float4*)&xs[lane][0];
#pragma unroll
            for (int j = 0; j < 8; j++) {
                float4 v = rr[j];
                cA = __builtin_elementwise_fma(qpA[4 * j + 0], splat2(v.x), cA);
                cB = __builtin_elementwise_fma(qpB[4 * j + 0], splat2(v.x), cB);
                cA = __builtin_elementwise_fma(qpA[4 * j + 1], splat2(v.y), cA);
                cB = __builtin_elementwise_fma(qpB[4 * j + 1], splat2(v.y), cB);
                cA = __builtin_elementwise_fma(qpA[4 * j + 2], splat2(v.z), cA);
                cB = __builtin_elementwise_fma(qpB[4 * j + 2], splat2(v.z), cB);
                cA = __builtin_elementwise_fma(qpA[4 * j + 3], splat2(v.w), cA);
                cB = __builtin_elementwise_fma(qpB[4 * j + 3], splat2(v.w), cB);
            }
        }
        // ref combine order per half: (ssq + xq) - (c + c)
        v2f dA = (ssqA + splat2(xq_c)) - (cA + cA);
        v2f dB = (ssqB + splat2(xq_c)) - (cB + cB);
        int n = t * 64 + lane;
        insert_cand(dA.x, n, lane, bq0d, bq0i, cnt0, tau0);
        insert_cand(dA.y, n, lane, bq1d, bq1i, cnt1, tau1);
        insert_cand(dB.x, n, lane, bq2d, bq2i, cnt2, tau2);
        insert_cand(dB.y, n, lane, bq3d, bq3i, cnt3, tau3);
        __syncthreads();   // tile t reads done; next tile may overwrite xs
    }
    // final: compact (lex-sorts survivors) and emit first 32 per query
    wave_compact2(bq0d, bq0i, cnt0, lane);
    wave_compact2(bq1d, bq1i, cnt1, lane);
    wave_compact2(bq2d, bq2i, cnt2, lane);
    wave_compact2(bq3d, bq3i, cnt3, lane);
    int s = s0 + w * 4;
    if (lane < 32) {
        nbr[((size_t)b * SS + s) * KK + lane]     = bq0i[lane];
        nbr[((size_t)b * SS + s + 1) * KK + lane] = bq1i[lane];
        nbr[((size_t)b * SS + s + 2) * KK + lane] = bq2i[lane];
        nbr[((size_t)b * SS + s + 3) * KK + lane] = bq3i[lane];
    }
}

// ---------------------------------------------------------------------------
// K4: features_batch[b,o,s] = max_k h2[b, nbr[b,s,k], o]; block=128, 16 s/block
__global__ __launch_bounds__(128) void maxgather_kernel(const float* __restrict__ h2,
                                                        const int* __restrict__ nbr,
                                                        float* __restrict__ out_feat) {
    __shared__ float fs[128][17];
    int b = blockIdx.x & 7;
    int sg = blockIdx.x >> 3;               // 0..127
    int s0 = sg * 16;
    int tid = threadIdx.x;                  // o = tid (0..127)
    for (int si = 0; si < 16; si++) {
        int s = s0 + si;
        const int* row = nbr + ((size_t)b * SS + s) * KK;
        float m = -INFINITY;
#pragma unroll 4
        for (int k = 0; k < KK; k++) {
            int idx = row[k];
            float v = h2[((size_t)b * NN + idx) * OUTC + tid];
            m = fmaxf(m, v);
        }
        fs[tid][si] = m;
    }
    __syncthreads();
#pragma unroll
    for (int j = 0; j < 16; j++) {
        int flat = j * 128 + tid;
        int fo = flat >> 4, sw = flat & 15;
        out_feat[((size_t)b * OUTC + fo) * SS + s0 + sw] = fs[fo][sw];
    }
}

// ---------------------------------------------------------------------------
extern "C" void kernel_launch(void* const* d_in, const int* in_sizes, int n_in,
                              void* d_out, int out_size, void* d_ws, size_t ws_size,
                              hipStream_t stream) {
    const float* x    = (const float*)d_in[0];
    const int*   sidx = (const int*)d_in[1];
    const float* W1   = (const float*)d_in[2];
    const float* b1   = (const float*)d_in[3];
    const float* W2   = (const float*)d_in[4];
    const float* b2   = (const float*)d_in[5];

    float* out_feat = (float*)d_out;                       // [B,128,S]
    float* out_samp = out_feat + (size_t)BB * OUTC * SS;   // [B,32,S]

    float* h2      = (float*)d_ws;                         // B*N*128 fp32 = 64 MB
    float* sampled = h2 + (size_t)BB * NN * OUTC;          // B*S*F
    float* xsq     = sampled + (size_t)BB * SS * FF;       // B*N
    float* ssq     = xsq + (size_t)BB * NN;                // B*S
    int*   nbr     = (int*)(ssq + (size_t)BB * SS);        // B*S*K

    xsq_kernel<<<dim3(BB * NN / 256), dim3(256), 0, stream>>>(x, xsq);
    gather_kernel<<<dim3(BB * SS / 256), dim3(256), 0, stream>>>(x, sidx, sampled, ssq);
    mlp_kernel<<<dim3(BB * NN / 64), dim3(256), 0, stream>>>(x, W1, b1, W2, b2, h2);
    transpose_kernel<<<dim3(BB * SS / 64), dim3(256), 0, stream>>>(sampled, out_samp);
    topk_kernel<<<dim3(BB * SS / 16), dim3(256), 0, stream>>>(x, xsq, sampled, ssq, nbr);
    maxgather_kernel<<<dim3(BB * SS / 16), dim3(128), 0, stream>>>(h2, nbr, out_feat);
}

// Round 7
// 926.793 us; speedup vs baseline: 2.3128x; 1.2369x over previous
//
#include <hip/hip_runtime.h>
#include <math.h>

#pragma clang fp contract(off)   // no implicit fusion; FMA only where ref has it

// Problem constants (fixed by the reference)
#define BB   8
#define NN   16384
#define FF   32
#define SS   2048
#define KK   32
#define OUTC 128

typedef float v2f __attribute__((ext_vector_type(2)));

// force a value into uniform (SGPR) representation
__device__ __forceinline__ float uni(float v) {
    return __uint_as_float(__builtin_amdgcn_readfirstlane(__float_as_uint(v)));
}

__device__ __forceinline__ v2f splat2(float s) { v2f r; r.x = s; r.y = s; return r; }

// prefix popcount of 64-bit ballot below this lane (2 VALU ops)
__device__ __forceinline__ int mbcnt64(unsigned long long m) {
    return __builtin_amdgcn_mbcnt_hi((unsigned)(m >> 32),
           __builtin_amdgcn_mbcnt_lo((unsigned)m, 0));
}

// ---------------------------------------------------------------------------
// Reference-bit-exact fp32 helpers (validated R0-R7):
// x_sq / s_sq: numpy pairwise_sum scalar 8-accumulator block (n=32, no FMA)
__device__ __forceinline__ float np_sumsq32(const float* a) {
    float r[8];
#pragma unroll
    for (int j = 0; j < 8; j++) r[j] = a[j] * a[j];
#pragma unroll
    for (int t = 1; t < 4; t++) {
#pragma unroll
        for (int j = 0; j < 8; j++) {
            float e = a[8 * t + j] * a[8 * t + j];
            r[j] = r[j] + e;
        }
    }
    return ((r[0] + r[1]) + (r[2] + r[3])) + ((r[4] + r[5]) + (r[6] + r[7]));
}

// ---------------------------------------------------------------------------
// K1a: x_sq[b,n] = ref-order sum_f x^2
__global__ __launch_bounds__(256) void xsq_kernel(const float* __restrict__ x,
                                                  float* __restrict__ xsq) {
    int gid = blockIdx.x * 256 + threadIdx.x;      // < B*N
    const float4* r = (const float4*)(x + (size_t)gid * FF);
    float a[32];
#pragma unroll
    for (int j = 0; j < 8; j++) {
        float4 v = r[j];
        a[4 * j] = v.x; a[4 * j + 1] = v.y; a[4 * j + 2] = v.z; a[4 * j + 3] = v.w;
    }
    xsq[gid] = np_sumsq32(a);
}

// ---------------------------------------------------------------------------
// K1b: gather sampled features (row-major [B,S,F]) + ref-order s_sq
__global__ __launch_bounds__(256) void gather_kernel(const float* __restrict__ x,
                                                     const int* __restrict__ sidx,
                                                     float* __restrict__ sampled,
                                                     float* __restrict__ ssq) {
    int gid = blockIdx.x * 256 + threadIdx.x;      // < B*S
    int b = gid >> 11;
    int idx = sidx[gid];
    const float4* r = (const float4*)(x + ((size_t)b * NN + idx) * FF);
    float4* wo = (float4*)(sampled + (size_t)gid * FF);
    float a[32];
#pragma unroll
    for (int j = 0; j < 8; j++) {
        float4 v = r[j];
        a[4 * j] = v.x; a[4 * j + 1] = v.y; a[4 * j + 2] = v.z; a[4 * j + 3] = v.w;
        wo[j] = v;
    }
    ssq[gid] = np_sumsq32(a);
}

// ---------------------------------------------------------------------------
// K1c: sampled [B,S,F] -> output sampled_batch [B,F,S] (transpose via LDS)
__global__ __launch_bounds__(256) void transpose_kernel(const float* __restrict__ sampled,
                                                        float* __restrict__ out_samp) {
    __shared__ float tile[32][65];
    int b = blockIdx.x >> 5, sg = blockIdx.x & 31;
    int s0 = sg * 64;
    int tid = threadIdx.x;
    int f = tid & 31, si = tid >> 5;               // si in 0..7
#pragma unroll
    for (int r = 0; r < 8; r++) {
        int s = r * 8 + si;
        tile[f][s] = sampled[((size_t)b * SS + s0 + s) * FF + f];
    }
    __syncthreads();
#pragma unroll
    for (int r = 0; r < 8; r++) {
        int flat = r * 256 + tid;
        int fo = flat >> 6, sw = flat & 63;
        out_samp[((size_t)b * FF + fo) * SS + s0 + sw] = tile[fo][sw];
    }
}

// ---------------------------------------------------------------------------
// K1d: x [B,N,F] -> BLOCKED transpose xt[b][t][f][64], t = n/64.
// Gives topk per-f loads at base + f*256B + lane*4B: coalesced 256 B
// requests, immediate-offset addressing, no LDS broadcast needed.
__global__ __launch_bounds__(256) void transpose_x_kernel(const float* __restrict__ x,
                                                          float* __restrict__ xt) {
    __shared__ float tile[32][65];
    int b = blockIdx.x >> 8;                // B*256 blocks
    int tg = blockIdx.x & 255;              // tile index t
    int n0 = tg * 64;
    int tid = threadIdx.x;
    int f = tid & 31, si = tid >> 5;        // si in 0..7
#pragma unroll
    for (int r = 0; r < 8; r++) {
        int n = r * 8 + si;
        tile[f][n] = x[((size_t)b * NN + n0 + n) * FF + f];
    }
    __syncthreads();
    float* wo = xt + (((size_t)b * 256 + tg) * 32) * 64;   // 2048 floats/tile
#pragma unroll
    for (int r = 0; r < 8; r++) {
        int flat = r * 256 + tid;           // = f*64 + l
        wo[flat] = tile[flat >> 6][flat & 63];
    }
}

// ---------------------------------------------------------------------------
// K2: per-point MLP, h2[b,n,:] = W2 @ relu(W1 @ x + b1) + b2  (fp32, VALU)
__global__ __launch_bounds__(256) void mlp_kernel(const float* __restrict__ x,
                                                  const float* __restrict__ W1,
                                                  const float* __restrict__ b1,
                                                  const float* __restrict__ W2,
                                                  const float* __restrict__ b2,
                                                  float* __restrict__ h2) {
    __shared__ float xs[64][36];          // padded
    __shared__ float hs[8512];            // h1t [128][65] then reused as h2s [64][133]
    int tid = threadIdx.x, lane = tid & 63;
    int wu = __builtin_amdgcn_readfirstlane(tid >> 6);
    size_t p0 = (size_t)blockIdx.x * 64;

    for (int i = tid; i < 64 * 8; i += 256) {
        int row = i >> 3, seg = i & 7;
        *(float4*)&xs[row][seg * 4] = *(const float4*)(x + (p0 + row) * FF + seg * 4);
    }
    __syncthreads();

    float xr[32];
    {
        const float4* r = (const float4*)&xs[lane][0];
#pragma unroll
        for (int j = 0; j < 8; j++) {
            float4 v = r[j];
            xr[4 * j] = v.x; xr[4 * j + 1] = v.y; xr[4 * j + 2] = v.z; xr[4 * j + 3] = v.w;
        }
    }
#pragma unroll 4
    for (int i = 0; i < 32; i++) {
        int o = wu * 32 + i;
        const float4* wr = (const float4*)(W1 + o * FF);
        float a = b1[o];
#pragma unroll
        for (int j = 0; j < 8; j++) {
            float4 v = wr[j];
            a = fmaf(v.x, xr[4 * j], a);     a = fmaf(v.y, xr[4 * j + 1], a);
            a = fmaf(v.z, xr[4 * j + 2], a); a = fmaf(v.w, xr[4 * j + 3], a);
        }
        hs[o * 65 + lane] = fmaxf(a, 0.f);
    }
    __syncthreads();
    float acc[32];
#pragma unroll
    for (int i = 0; i < 32; i++) acc[i] = b2[wu * 32 + i];
    for (int k4 = 0; k4 < 32; k4++) {
        float h0 = hs[(4 * k4 + 0) * 65 + lane];
        float h1v = hs[(4 * k4 + 1) * 65 + lane];
        float h2v = hs[(4 * k4 + 2) * 65 + lane];
        float h3v = hs[(4 * k4 + 3) * 65 + lane];
#pragma unroll
        for (int i = 0; i < 32; i++) {
            const float4 v = *(const float4*)(W2 + (wu * 32 + i) * OUTC + 4 * k4);
            acc[i] = fmaf(v.x, h0, acc[i]);  acc[i] = fmaf(v.y, h1v, acc[i]);
            acc[i] = fmaf(v.z, h2v, acc[i]); acc[i] = fmaf(v.w, h3v, acc[i]);
        }
    }
    __syncthreads();
#pragma unroll 4
    for (int i = 0; i < 32; i++) hs[lane * 133 + wu * 32 + i] = acc[i];
    __syncthreads();
    for (int j = 0; j < 32; j++) {
        int flat = j * 256 + tid;
        int p = flat >> 7, o = flat & 127;
        h2[(p0 + p) * OUTC + o] = hs[p * 133 + o];
    }
}

// ---------------------------------------------------------------------------
// K3 v10: register-direct distance loop over BLOCKED-TRANSPOSED x.
// R6 post-mortem: R4-structure wall is the LDS pipe (8 ds_read_b128 + 2
// ds_write per wave-tile = ~112 cyc on the single 128B/clk pipe -> 382 us/CU
// of 783); 4q/wave failed on SGPR-file overflow (qpB rematerialized in-loop).
// R5 failed only on coalescing (per-lane ROW loads). v10: xt[b][t][f][64]
// makes the 32 per-f loads coalesced (256 B requests) with imm-offset
// addressing; x panel L2-resident (2 MB/XCD via batch swizzle). NO LDS in
// the distance path, NO barriers (bufd/bufi per-wave), waves independent.
// Per-CU budget: VMEM issue ~110 us, VALU ~110 us, L2 BW 7 of 34 TB/s.
__device__ __forceinline__ bool lessp(float da, int ia, float db, int ib) {
    return da < db || (da == db && ia < ib);
}
__device__ __forceinline__ void cswap(float& d, int& i, int j, bool dirAsc, int lane) {
    float od = __shfl_xor(d, j);
    int   oi = __shfl_xor(i, j);
    bool lower = (lane & j) == 0;
    bool oLess = lessp(od, oi, d, i);
    if (oLess == (lower == dirAsc)) { d = od; i = oi; }
}
__device__ __forceinline__ void sort64(float& d, int& i, bool asc, int lane) {
#pragma unroll
    for (int k = 2; k <= 64; k <<= 1) {
        bool ba = (((lane & k) == 0) == asc);
#pragma unroll
        for (int j = k >> 1; j > 0; j >>= 1) cswap(d, i, j, ba, lane);
    }
}
// sort m valid slots, keep lowest-64 lex-sorted in [0,64); return 32nd-smallest
__device__ __forceinline__ float wave_compact2(float* bd, int* bi, int m, int lane) {
    float d0 = (lane < m) ? bd[lane] : INFINITY;
    int   i0 = (lane < m) ? bi[lane] : 0x7fffffff;
    float d1 = (lane + 64 < m) ? bd[lane + 64] : INFINITY;
    int   i1 = (lane + 64 < m) ? bi[lane + 64] : 0x7fffffff;
    sort64(d0, i0, true, lane);
    sort64(d1, i1, false, lane);
    bool t = lessp(d1, i1, d0, i0);
    float ld = t ? d1 : d0;
    int   li = t ? i1 : i0;
#pragma unroll
    for (int j = 32; j > 0; j >>= 1) cswap(ld, li, j, true, lane);
    bd[lane] = ld; bi[lane] = li;
    return uni(__shfl(ld, 31));            // uniform across wave
}

__device__ __forceinline__ void insert_cand(float dv, int n, int lane,
                                            float* bd, int* bi, int& cnt, float& tau) {
    unsigned long long m = __ballot(dv < tau);
    if (m) {
        int pos = cnt + mbcnt64(m);
        if (dv < tau) { bd[pos] = dv; bi[pos] = n; }
        cnt += __builtin_popcountll(m);
        if (cnt > 64) { tau = wave_compact2(bd, bi, cnt, lane); cnt = 32; }
    }
}

__global__ __launch_bounds__(256, 6) void topk_kernel(const float* __restrict__ xt,
                                                      const float* __restrict__ x_sq,
                                                      const float* __restrict__ sampled,
                                                      const float* __restrict__ s_sq,
                                                      int* __restrict__ nbr) {
    int b = blockIdx.x & 7;                 // XCD-by-batch swizzle
    int qg = blockIdx.x >> 3;               // 0..255
    int tid = threadIdx.x, lane = tid & 63;
    int w = __builtin_amdgcn_readfirstlane(tid >> 6);
    __shared__ float bufd[8][128];
    __shared__ int   bufi[8][128];
    int s0 = qg * 8;                        // 8 queries per block, 2 per wave
    const float* xtb = xt + (size_t)b * (NN * FF);   // blocked [256][32][64]
    const float* xqb = x_sq + (size_t)b * NN;

    // 2 query feature vectors, packed {q0,q1} pairs -> wave-uniform (SGPR pairs)
    v2f qp[32];
    {
        const float* sp0 = sampled + ((size_t)b * SS + s0 + w * 2 + 0) * FF;
        const float* sp1 = sampled + ((size_t)b * SS + s0 + w * 2 + 1) * FF;
#pragma unroll
        for (int k = 0; k < 32; k++) {
            qp[k].x = uni(sp0[k]);
            qp[k].y = uni(sp1[k]);
        }
    }
    v2f ssq01;
    ssq01.x = uni(s_sq[b * SS + s0 + w * 2 + 0]);
    ssq01.y = uni(s_sq[b * SS + s0 + w * 2 + 1]);

    float* bq0d = &bufd[w * 2 + 0][0];  int* bq0i = &bufi[w * 2 + 0][0];
    float* bq1d = &bufd[w * 2 + 1][0];  int* bq1i = &bufi[w * 2 + 1][0];
    int   cnt0 = 0, cnt1 = 0;              // wave-uniform (ballot popcounts)
    float tau0 = INFINITY, tau1 = INFINITY;

    float xqv = xqb[lane];

    for (int t = 0; t < NN / 64; t++) {
        // lane handles point n = t*64+lane; 32 coalesced per-f loads at
        // imm offsets f*256B from a single per-lane base.
        const float* pn = xtb + (size_t)t * 2048 + lane;
        float xq_c = xqv;
        v2f c01; c01.x = 0.f; c01.y = 0.f;
#pragma unroll
        for (int j = 0; j < 32; j++) {
            float v = pn[j * 64];
            // each half is the ref-exact sequential FMA order f=0..31
            c01 = __builtin_elementwise_fma(qp[j], splat2(v), c01);
        }
        if (t + 1 < NN / 64) xqv = xqb[(t + 1) * 64 + lane];

        // ref combine order per half: (ssq + xq) - (c + c)
        v2f d01 = (ssq01 + splat2(xq_c)) - (c01 + c01);
        int n = t * 64 + lane;
        insert_cand(d01.x, n, lane, bq0d, bq0i, cnt0, tau0);
        insert_cand(d01.y, n, lane, bq1d, bq1i, cnt1, tau1);
    }
    // final: compact (lex-sorts survivors) and emit first 32 per query
    wave_compact2(bq0d, bq0i, cnt0, lane);
    wave_compact2(bq1d, bq1i, cnt1, lane);
    int s = s0 + w * 2;
    if (lane < 32) {
        nbr[((size_t)b * SS + s) * KK + lane] = bq0i[lane];
        nbr[((size_t)b * SS + s + 1) * KK + lane] = bq1i[lane];
    }
}

// ---------------------------------------------------------------------------
// K4: features_batch[b,o,s] = max_k h2[b, nbr[b,s,k], o]; block=128, 16 s/block
__global__ __launch_bounds__(128) void maxgather_kernel(const float* __restrict__ h2,
                                                        const int* __restrict__ nbr,
                                                        float* __restrict__ out_feat) {
    __shared__ float fs[128][17];
    int b = blockIdx.x & 7;
    int sg = blockIdx.x >> 3;               // 0..127
    int s0 = sg * 16;
    int tid = threadIdx.x;                  // o = tid (0..127)
    for (int si = 0; si < 16; si++) {
        int s = s0 + si;
        const int* row = nbr + ((size_t)b * SS + s) * KK;
        float m = -INFINITY;
#pragma unroll 4
        for (int k = 0; k < KK; k++) {
            int idx = row[k];
            float v = h2[((size_t)b * NN + idx) * OUTC + tid];
            m = fmaxf(m, v);
        }
        fs[tid][si] = m;
    }
    __syncthreads();
#pragma unroll
    for (int j = 0; j < 16; j++) {
        int flat = j * 128 + tid;
        int fo = flat >> 4, sw = flat & 15;
        out_feat[((size_t)b * OUTC + fo) * SS + s0 + sw] = fs[fo][sw];
    }
}

// ---------------------------------------------------------------------------
extern "C" void kernel_launch(void* const* d_in, const int* in_sizes, int n_in,
                              void* d_out, int out_size, void* d_ws, size_t ws_size,
                              hipStream_t stream) {
    const float* x    = (const float*)d_in[0];
    const int*   sidx = (const int*)d_in[1];
    const float* W1   = (const float*)d_in[2];
    const float* b1   = (const float*)d_in[3];
    const float* W2   = (const float*)d_in[4];
    const float* b2   = (const float*)d_in[5];

    float* out_feat = (float*)d_out;                       // [B,128,S]
    float* out_samp = out_feat + (size_t)BB * OUTC * SS;   // [B,32,S]

    float* h2      = (float*)d_ws;                         // B*N*128 fp32 = 64 MB
    float* sampled = h2 + (size_t)BB * NN * OUTC;          // B*S*F
    float* xsq     = sampled + (size_t)BB * SS * FF;       // B*N
    float* ssq     = xsq + (size_t)BB * NN;                // B*S
    int*   nbr     = (int*)(ssq + (size_t)BB * SS);        // B*S*K
    // xt (16.8 MB) ALIASES the h2 region (64 MB): topk consumes xt strictly
    // before mlp writes h2 (same stream, ordered). No extra workspace.
    float* xt      = h2;

    xsq_kernel<<<dim3(BB * NN / 256), dim3(256), 0, stream>>>(x, xsq);
    gather_kernel<<<dim3(BB * SS / 256), dim3(256), 0, stream>>>(x, sidx, sampled, ssq);
    transpose_kernel<<<dim3(BB * SS / 64), dim3(256), 0, stream>>>(sampled, out_samp);
    transpose_x_kernel<<<dim3(BB * 256), dim3(256), 0, stream>>>(x, xt);
    topk_kernel<<<dim3(BB * SS / 8), dim3(256), 0, stream>>>(xt, xsq, sampled, ssq, nbr);
    mlp_kernel<<<dim3(BB * NN / 64), dim3(256), 0, stream>>>(x, W1, b1, W2, b2, h2);
    maxgather_kernel<<<dim3(BB * SS / 16), dim3(128), 0, stream>>>(h2, nbr, out_feat);
}

// Round 8
// 902.735 us; speedup vs baseline: 2.3744x; 1.0266x over previous
//
#include <hip/hip_runtime.h>
#include <math.h>

#pragma clang fp contract(off)   // no implicit fusion; FMA only where ref has it

// Problem constants (fixed by the reference)
#define BB   8
#define NN   16384
#define FF   32
#define SS   2048
#define KK   32
#define OUTC 128

typedef float v2f __attribute__((ext_vector_type(2)));

// force a value into uniform (SGPR) representation
__device__ __forceinline__ float uni(float v) {
    return __uint_as_float(__builtin_amdgcn_readfirstlane(__float_as_uint(v)));
}

__device__ __forceinline__ v2f splat2(float s) { v2f r; r.x = s; r.y = s; return r; }

// prefix popcount of 64-bit ballot below this lane (2 VALU ops)
__device__ __forceinline__ int mbcnt64(unsigned long long m) {
    return __builtin_amdgcn_mbcnt_hi((unsigned)(m >> 32),
           __builtin_amdgcn_mbcnt_lo((unsigned)m, 0));
}

// ---------------------------------------------------------------------------
// Reference-bit-exact fp32 helpers (validated R0-R7):
// x_sq / s_sq: numpy pairwise_sum scalar 8-accumulator block (n=32, no FMA)
__device__ __forceinline__ float np_sumsq32(const float* a) {
    float r[8];
#pragma unroll
    for (int j = 0; j < 8; j++) r[j] = a[j] * a[j];
#pragma unroll
    for (int t = 1; t < 4; t++) {
#pragma unroll
        for (int j = 0; j < 8; j++) {
            float e = a[8 * t + j] * a[8 * t + j];
            r[j] = r[j] + e;
        }
    }
    return ((r[0] + r[1]) + (r[2] + r[3])) + ((r[4] + r[5]) + (r[6] + r[7]));
}

// ---------------------------------------------------------------------------
// K1a: x_sq[b,n] = ref-order sum_f x^2
__global__ __launch_bounds__(256) void xsq_kernel(const float* __restrict__ x,
                                                  float* __restrict__ xsq) {
    int gid = blockIdx.x * 256 + threadIdx.x;      // < B*N
    const float4* r = (const float4*)(x + (size_t)gid * FF);
    float a[32];
#pragma unroll
    for (int j = 0; j < 8; j++) {
        float4 v = r[j];
        a[4 * j] = v.x; a[4 * j + 1] = v.y; a[4 * j + 2] = v.z; a[4 * j + 3] = v.w;
    }
    xsq[gid] = np_sumsq32(a);
}

// ---------------------------------------------------------------------------
// K1b: gather sampled features (row-major [B,S,F]) + ref-order s_sq
__global__ __launch_bounds__(256) void gather_kernel(const float* __restrict__ x,
                                                     const int* __restrict__ sidx,
                                                     float* __restrict__ sampled,
                                                     float* __restrict__ ssq) {
    int gid = blockIdx.x * 256 + threadIdx.x;      // < B*S
    int b = gid >> 11;
    int idx = sidx[gid];
    const float4* r = (const float4*)(x + ((size_t)b * NN + idx) * FF);
    float4* wo = (float4*)(sampled + (size_t)gid * FF);
    float a[32];
#pragma unroll
    for (int j = 0; j < 8; j++) {
        float4 v = r[j];
        a[4 * j] = v.x; a[4 * j + 1] = v.y; a[4 * j + 2] = v.z; a[4 * j + 3] = v.w;
        wo[j] = v;
    }
    ssq[gid] = np_sumsq32(a);
}

// ---------------------------------------------------------------------------
// K1c: sampled [B,S,F] -> output sampled_batch [B,F,S] (transpose via LDS)
__global__ __launch_bounds__(256) void transpose_kernel(const float* __restrict__ sampled,
                                                        float* __restrict__ out_samp) {
    __shared__ float tile[32][65];
    int b = blockIdx.x >> 5, sg = blockIdx.x & 31;
    int s0 = sg * 64;
    int tid = threadIdx.x;
    int f = tid & 31, si = tid >> 5;               // si in 0..7
#pragma unroll
    for (int r = 0; r < 8; r++) {
        int s = r * 8 + si;
        tile[f][s] = sampled[((size_t)b * SS + s0 + s) * FF + f];
    }
    __syncthreads();
#pragma unroll
    for (int r = 0; r < 8; r++) {
        int flat = r * 256 + tid;
        int fo = flat >> 6, sw = flat & 63;
        out_samp[((size_t)b * FF + fo) * SS + s0 + sw] = tile[fo][sw];
    }
}

// ---------------------------------------------------------------------------
// K1d v2: x [B,N,F] -> float4-PACKED blocked transpose
// xt[b][t][j][l] (float4), j = f/4, l = lane: point n = t*64+l's features
// 4j..4j+3 sit contiguously at ((t*8+j)*64 + l)*16B. topk lane loads ONE
// global_load_dwordx4 per j: 64 lanes x 16B = 1024B fully coalesced; 8
// load instrs per tile instead of 32 scalar ones (R7 issue-bound fix).
__global__ __launch_bounds__(256) void transpose_x_kernel(const float* __restrict__ x,
                                                          float* __restrict__ xt) {
    __shared__ float tile[32][65];
    int b = blockIdx.x >> 8;                // B*256 blocks
    int tg = blockIdx.x & 255;              // tile index t
    int n0 = tg * 64;
    int tid = threadIdx.x;
    int f = tid & 31, si = tid >> 5;        // si in 0..7
#pragma unroll
    for (int r = 0; r < 8; r++) {
        int n = r * 8 + si;
        tile[f][n] = x[((size_t)b * NN + n0 + n) * FF + f];
    }
    __syncthreads();
    float* wo = xt + (((size_t)b * 256 + tg) * 2048);   // 2048 floats/tile
#pragma unroll
    for (int r = 0; r < 8; r++) {
        int flat = r * 256 + tid;           // = j*256 + l*4 + e  (j = r)
        int e = flat & 3, l = (flat >> 2) & 63;
        wo[flat] = tile[4 * r + e][l];
    }
}

// ---------------------------------------------------------------------------
// K2: per-point MLP, h2[b,n,:] = W2 @ relu(W1 @ x + b1) + b2  (fp32, VALU)
__global__ __launch_bounds__(256) void mlp_kernel(const float* __restrict__ x,
                                                  const float* __restrict__ W1,
                                                  const float* __restrict__ b1,
                                                  const float* __restrict__ W2,
                                                  const float* __restrict__ b2,
                                                  float* __restrict__ h2) {
    __shared__ float xs[64][36];          // padded
    __shared__ float hs[8512];            // h1t [128][65] then reused as h2s [64][133]
    int tid = threadIdx.x, lane = tid & 63;
    int wu = __builtin_amdgcn_readfirstlane(tid >> 6);
    size_t p0 = (size_t)blockIdx.x * 64;

    for (int i = tid; i < 64 * 8; i += 256) {
        int row = i >> 3, seg = i & 7;
        *(float4*)&xs[row][seg * 4] = *(const float4*)(x + (p0 + row) * FF + seg * 4);
    }
    __syncthreads();

    float xr[32];
    {
        const float4* r = (const float4*)&xs[lane][0];
#pragma unroll
        for (int j = 0; j < 8; j++) {
            float4 v = r[j];
            xr[4 * j] = v.x; xr[4 * j + 1] = v.y; xr[4 * j + 2] = v.z; xr[4 * j + 3] = v.w;
        }
    }
#pragma unroll 4
    for (int i = 0; i < 32; i++) {
        int o = wu * 32 + i;
        const float4* wr = (const float4*)(W1 + o * FF);
        float a = b1[o];
#pragma unroll
        for (int j = 0; j < 8; j++) {
            float4 v = wr[j];
            a = fmaf(v.x, xr[4 * j], a);     a = fmaf(v.y, xr[4 * j + 1], a);
            a = fmaf(v.z, xr[4 * j + 2], a); a = fmaf(v.w, xr[4 * j + 3], a);
        }
        hs[o * 65 + lane] = fmaxf(a, 0.f);
    }
    __syncthreads();
    float acc[32];
#pragma unroll
    for (int i = 0; i < 32; i++) acc[i] = b2[wu * 32 + i];
    for (int k4 = 0; k4 < 32; k4++) {
        float h0 = hs[(4 * k4 + 0) * 65 + lane];
        float h1v = hs[(4 * k4 + 1) * 65 + lane];
        float h2v = hs[(4 * k4 + 2) * 65 + lane];
        float h3v = hs[(4 * k4 + 3) * 65 + lane];
#pragma unroll
        for (int i = 0; i < 32; i++) {
            const float4 v = *(const float4*)(W2 + (wu * 32 + i) * OUTC + 4 * k4);
            acc[i] = fmaf(v.x, h0, acc[i]);  acc[i] = fmaf(v.y, h1v, acc[i]);
            acc[i] = fmaf(v.z, h2v, acc[i]); acc[i] = fmaf(v.w, h3v, acc[i]);
        }
    }
    __syncthreads();
#pragma unroll 4
    for (int i = 0; i < 32; i++) hs[lane * 133 + wu * 32 + i] = acc[i];
    __syncthreads();
    for (int j = 0; j < 32; j++) {
        int flat = j * 256 + tid;
        int p = flat >> 7, o = flat & 127;
        h2[(p0 + p) * OUTC + o] = hs[p * 133 + o];
    }
}

// ---------------------------------------------------------------------------
// K3 v11: register-direct distance loop over float4-PACKED transposed x.
// R7 post-mortem: v10 works (665us, best) but issues 32 scalar
// global_load_dword per wave-tile (~109us/CU VMEM issue + addr VALU for
// offsets >4095B + waitcnt stalls). v11 loads the same bytes as 8
// global_load_dwordx4 (1024B/instr coalesced) from xt[b][t][j][l](float4).
// FMA consumption stays in exact f=0..31 order -> bit-identical distances.
// Still: no LDS in distance path, no barriers, waves independent.
__device__ __forceinline__ bool lessp(float da, int ia, float db, int ib) {
    return da < db || (da == db && ia < ib);
}
__device__ __forceinline__ void cswap(float& d, int& i, int j, bool dirAsc, int lane) {
    float od = __shfl_xor(d, j);
    int   oi = __shfl_xor(i, j);
    bool lower = (lane & j) == 0;
    bool oLess = lessp(od, oi, d, i);
    if (oLess == (lower == dirAsc)) { d = od; i = oi; }
}
__device__ __forceinline__ void sort64(float& d, int& i, bool asc, int lane) {
#pragma unroll
    for (int k = 2; k <= 64; k <<= 1) {
        bool ba = (((lane & k) == 0) == asc);
#pragma unroll
        for (int j = k >> 1; j > 0; j >>= 1) cswap(d, i, j, ba, lane);
    }
}
// sort m valid slots, keep lowest-64 lex-sorted in [0,64); return 32nd-smallest
__device__ __forceinline__ float wave_compact2(float* bd, int* bi, int m, int lane) {
    float d0 = (lane < m) ? bd[lane] : INFINITY;
    int   i0 = (lane < m) ? bi[lane] : 0x7fffffff;
    float d1 = (lane + 64 < m) ? bd[lane + 64] : INFINITY;
    int   i1 = (lane + 64 < m) ? bi[lane + 64] : 0x7fffffff;
    sort64(d0, i0, true, lane);
    sort64(d1, i1, false, lane);
    bool t = lessp(d1, i1, d0, i0);
    float ld = t ? d1 : d0;
    int   li = t ? i1 : i0;
#pragma unroll
    for (int j = 32; j > 0; j >>= 1) cswap(ld, li, j, true, lane);
    bd[lane] = ld; bi[lane] = li;
    return uni(__shfl(ld, 31));            // uniform across wave
}

__device__ __forceinline__ void insert_cand(float dv, int n, int lane,
                                            float* bd, int* bi, int& cnt, float& tau) {
    unsigned long long m = __ballot(dv < tau);
    if (m) {
        int pos = cnt + mbcnt64(m);
        if (dv < tau) { bd[pos] = dv; bi[pos] = n; }
        cnt += __builtin_popcountll(m);
        if (cnt > 64) { tau = wave_compact2(bd, bi, cnt, lane); cnt = 32; }
    }
}

__global__ __launch_bounds__(256, 6) void topk_kernel(const float* __restrict__ xt,
                                                      const float* __restrict__ x_sq,
                                                      const float* __restrict__ sampled,
                                                      const float* __restrict__ s_sq,
                                                      int* __restrict__ nbr) {
    int b = blockIdx.x & 7;                 // XCD-by-batch swizzle
    int qg = blockIdx.x >> 3;               // 0..255
    int tid = threadIdx.x, lane = tid & 63;
    int w = __builtin_amdgcn_readfirstlane(tid >> 6);
    __shared__ float bufd[8][128];
    __shared__ int   bufi[8][128];
    int s0 = qg * 8;                        // 8 queries per block, 2 per wave
    const float* xtb = xt + (size_t)b * (NN * FF);   // packed [256][8][64]f4
    const float* xqb = x_sq + (size_t)b * NN;

    // 2 query feature vectors, packed {q0,q1} pairs -> wave-uniform (SGPR pairs)
    v2f qp[32];
    {
        const float* sp0 = sampled + ((size_t)b * SS + s0 + w * 2 + 0) * FF;
        const float* sp1 = sampled + ((size_t)b * SS + s0 + w * 2 + 1) * FF;
#pragma unroll
        for (int k = 0; k < 32; k++) {
            qp[k].x = uni(sp0[k]);
            qp[k].y = uni(sp1[k]);
        }
    }
    v2f ssq01;
    ssq01.x = uni(s_sq[b * SS + s0 + w * 2 + 0]);
    ssq01.y = uni(s_sq[b * SS + s0 + w * 2 + 1]);

    float* bq0d = &bufd[w * 2 + 0][0];  int* bq0i = &bufi[w * 2 + 0][0];
    float* bq1d = &bufd[w * 2 + 1][0];  int* bq1i = &bufi[w * 2 + 1][0];
    int   cnt0 = 0, cnt1 = 0;              // wave-uniform (ballot popcounts)
    float tau0 = INFINITY, tau1 = INFINITY;

    float xqv = xqb[lane];

    for (int t = 0; t < NN / 64; t++) {
        // lane handles point n = t*64+lane; 8 coalesced dwordx4 loads at
        // imm offsets j*1024B from a single per-lane float4 base.
        const float4* pn = (const float4*)(xtb + (size_t)t * 2048) + lane;
        float4 vv[8];
#pragma unroll
        for (int j = 0; j < 8; j++) vv[j] = pn[j * 64];
        float xq_c = xqv;
        v2f c01; c01.x = 0.f; c01.y = 0.f;
#pragma unroll
        for (int j = 0; j < 8; j++) {
            float4 v = vv[j];
            // each half is the ref-exact sequential FMA order f=0..31
            c01 = __builtin_elementwise_fma(qp[4 * j + 0], splat2(v.x), c01);
            c01 = __builtin_elementwise_fma(qp[4 * j + 1], splat2(v.y), c01);
            c01 = __builtin_elementwise_fma(qp[4 * j + 2], splat2(v.z), c01);
            c01 = __builtin_elementwise_fma(qp[4 * j + 3], splat2(v.w), c01);
        }
        if (t + 1 < NN / 64) xqv = xqb[(t + 1) * 64 + lane];

        // ref combine order per half: (ssq + xq) - (c + c)
        v2f d01 = (ssq01 + splat2(xq_c)) - (c01 + c01);
        int n = t * 64 + lane;
        insert_cand(d01.x, n, lane, bq0d, bq0i, cnt0, tau0);
        insert_cand(d01.y, n, lane, bq1d, bq1i, cnt1, tau1);
    }
    // final: compact (lex-sorts survivors) and emit first 32 per query
    wave_compact2(bq0d, bq0i, cnt0, lane);
    wave_compact2(bq1d, bq1i, cnt1, lane);
    int s = s0 + w * 2;
    if (lane < 32) {
        nbr[((size_t)b * SS + s) * KK + lane] = bq0i[lane];
        nbr[((size_t)b * SS + s + 1) * KK + lane] = bq1i[lane];
    }
}

// ---------------------------------------------------------------------------
// K4: features_batch[b,o,s] = max_k h2[b, nbr[b,s,k], o]; block=128, 16 s/block
__global__ __launch_bounds__(128) void maxgather_kernel(const float* __restrict__ h2,
                                                        const int* __restrict__ nbr,
                                                        float* __restrict__ out_feat) {
    __shared__ float fs[128][17];
    int b = blockIdx.x & 7;
    int sg = blockIdx.x >> 3;               // 0..127
    int s0 = sg * 16;
    int tid = threadIdx.x;                  // o = tid (0..127)
    for (int si = 0; si < 16; si++) {
        int s = s0 + si;
        const int* row = nbr + ((size_t)b * SS + s) * KK;
        float m = -INFINITY;
#pragma unroll 4
        for (int k = 0; k < KK; k++) {
            int idx = row[k];
            float v = h2[((size_t)b * NN + idx) * OUTC + tid];
            m = fmaxf(m, v);
        }
        fs[tid][si] = m;
    }
    __syncthreads();
#pragma unroll
    for (int j = 0; j < 16; j++) {
        int flat = j * 128 + tid;
        int fo = flat >> 4, sw = flat & 15;
        out_feat[((size_t)b * OUTC + fo) * SS + s0 + sw] = fs[fo][sw];
    }
}

// ---------------------------------------------------------------------------
extern "C" void kernel_launch(void* const* d_in, const int* in_sizes, int n_in,
                              void* d_out, int out_size, void* d_ws, size_t ws_size,
                              hipStream_t stream) {
    const float* x    = (const float*)d_in[0];
    const int*   sidx = (const int*)d_in[1];
    const float* W1   = (const float*)d_in[2];
    const float* b1   = (const float*)d_in[3];
    const float* W2   = (const float*)d_in[4];
    const float* b2   = (const float*)d_in[5];

    float* out_feat = (float*)d_out;                       // [B,128,S]
    float* out_samp = out_feat + (size_t)BB * OUTC * SS;   // [B,32,S]

    float* h2      = (float*)d_ws;                         // B*N*128 fp32 = 64 MB
    float* sampled = h2 + (size_t)BB * NN * OUTC;          // B*S*F
    float* xsq     = sampled + (size_t)BB * SS * FF;       // B*N
    float* ssq     = xsq + (size_t)BB * NN;                // B*S
    int*   nbr     = (int*)(ssq + (size_t)BB * SS);        // B*S*K
    // xt (16.8 MB) ALIASES the h2 region (64 MB): topk consumes xt strictly
    // before mlp writes h2 (same stream, ordered). No extra workspace.
    float* xt      = h2;

    xsq_kernel<<<dim3(BB * NN / 256), dim3(256), 0, stream>>>(x, xsq);
    gather_kernel<<<dim3(BB * SS / 256), dim3(256), 0, stream>>>(x, sidx, sampled, ssq);
    transpose_kernel<<<dim3(BB * SS / 64), dim3(256), 0, stream>>>(sampled, out_samp);
    transpose_x_kernel<<<dim3(BB * 256), dim3(256), 0, stream>>>(x, xt);
    topk_kernel<<<dim3(BB * SS / 8), dim3(256), 0, stream>>>(xt, xsq, sampled, ssq, nbr);
    mlp_kernel<<<dim3(BB * NN / 64), dim3(256), 0, stream>>>(x, W1, b1, W2, b2, h2);
    maxgather_kernel<<<dim3(BB * SS / 16), dim3(128), 0, stream>>>(h2, nbr, out_feat);
}